// Round 4
// baseline (38407.153 us; speedup 1.0000x reference)
//
#include <hip/hip_runtime.h>
#include <hip/hip_cooperative_groups.h>

namespace cg = cooperative_groups;

// ---------------------------------------------------------------------------
// GRU (2-layer, B=64, T=1024, I=256, H=512) + FC(512->256). FP32 I/O per the
// reference (jnp.float32); bf16 used internally for MFMA operands only
// (threshold is 2% relative: bf16-compute path explicitly allowed).
// Single persistent cooperative kernel (256 WGs x 256 thr). Per time step one
// uniform MFMA GEMM C[64 x 4096] = A[64 x 1280] * Wp^T, A = [h0 | h1 | x(t+1)]
// staged bf16 in __device__ ping-pong buffers. Columns = {r,z,n_x,n_h} x 4u
// x 2 layers per WG; weights converted fp32->bf16 once into registers; fused
// gate epilogue with fp32 h-state in registers; FC fused (64 WGs, 16x16
// tiles, fp32 out). One grid.sync per step.
// ---------------------------------------------------------------------------

typedef __bf16 bf16x8 __attribute__((ext_vector_type(8)));
typedef unsigned short u16x8 __attribute__((ext_vector_type(8)));
typedef float f32x16 __attribute__((ext_vector_type(16)));
typedef float f32x4  __attribute__((ext_vector_type(4)));

// S ping-pong buffers: [2][64 b][1280 k] bf16 = 327,680 B in module .bss
__device__ __align__(16) unsigned short g_S[2 * 64 * 1280];

__device__ __forceinline__ unsigned short f2b(float f) {
    unsigned u = __float_as_uint(f);
    u += 0x7fffu + ((u >> 16) & 1u);          // round to nearest even
    return (unsigned short)(u >> 16);
}
__device__ __forceinline__ bf16x8 cvt8(const float* __restrict__ p) {
    union { u16x8 u; bf16x8 b; } cv;
    #pragma unroll
    for (int j = 0; j < 8; ++j) cv.u[j] = f2b(p[j]);
    return cv.b;
}
__device__ __forceinline__ float fsig(float x)  { return 1.0f / (1.0f + __expf(-x)); }
__device__ __forceinline__ float ftanh(float x) { return 1.0f - 2.0f / (__expf(2.0f * x) + 1.0f); }

__global__ __launch_bounds__(256, 1)
void gru_fused(const float* __restrict__ xin,   // [64][1024][256] fp32
               const float* __restrict__ Wih0, const float* __restrict__ bih0,
               const float* __restrict__ Whh0, const float* __restrict__ bhh0,
               const float* __restrict__ Wih1, const float* __restrict__ bih1,
               const float* __restrict__ Whh1, const float* __restrict__ bhh1,
               const float* __restrict__ Wfc,  const float* __restrict__ bfc,
               float* __restrict__ out)
{
    __shared__ float ldsC[4224];          // [4 waves][32 rows][33] (pad: conflict-free)
    cg::grid_group grid = cg::this_grid();

    const int th = threadIdx.x;
    const int wg = blockIdx.x;            // 256 WGs (cooperative: co-resident)
    const int bh = wg >> 7;               // batch half
    const int cg_ = wg & 127;             // column group: units 4cg..4cg+3, both layers
    const int v  = th >> 6;               // wave = K-split (320 k each)
    const int ln = th & 63;
    const int tid = wg * 256 + th;
    const int bloc = bh * 32;

    unsigned short* Sbuf0 = g_S;                  // [64 b][1280 k] bf16
    unsigned short* Sbuf1 = g_S + 64 * 1280;
    unsigned short* Sbuf[2] = {Sbuf0, Sbuf1};

    // ------------------------------------------------------------------ phase 0
    // zero h-regions (k<1024) of both S buffers; x(0) -> S0 x-region (cvt bf16)
    for (int e = tid; e < 131072; e += 65536) {
        int buf = e >> 16, r2 = e & 65535, b = r2 >> 10, k = r2 & 1023;
        Sbuf[buf][b * 1280 + k] = 0;
    }
    if (tid < 16384) {
        int b = tid >> 8, i = tid & 255;
        Sbuf0[b * 1280 + 1024 + i] = f2b(xin[(b * 1024 + 0) * 256 + i]);
    }

    // ------------------------- preload B-fragments from GLOBAL (fp32 -> bf16)
    // column n = cg*32 + nl; nl = lay*16 + ty*4 + p (lay 0=layer1, 1=layer0;
    // ty 0=r,1=z,2=n_x,3=n_h); k = v*320 + ks*16 + (ln>>5)*8 + j.
    // k-regions: [0,512)=h0, [512,1024)=h1, [1024,1280)=x.
    bf16x8 breg[20];
    {
        const int nl = ln & 31, lay = nl >> 4, ty = (nl >> 2) & 3, p = nl & 3;
        const int u = cg_ * 4 + p;
        const int kh = (ln >> 5) << 3;
        #pragma unroll
        for (int ks = 0; ks < 20; ++ks) {
            const int k = v * 320 + ks * 16 + kh;
            const float* src = nullptr;
            if (lay == 0) {                    // layer 1: input = h0, hidden = h1
                if (k < 512) {
                    if (ty != 3) src = Wih1 + (u + (ty == 1 ? 512 : (ty == 2 ? 1024 : 0))) * 512 + k;
                } else if (k < 1024) {
                    if (ty != 2) src = Whh1 + (u + (ty == 1 ? 512 : (ty == 3 ? 1024 : 0))) * 512 + (k - 512);
                }
            } else {                           // layer 0: hidden = h0, input = x
                if (k < 512) {
                    if (ty != 2) src = Whh0 + (u + (ty == 1 ? 512 : (ty == 3 ? 1024 : 0))) * 512 + k;
                } else if (k >= 1024) {
                    if (ty != 3) src = Wih0 + (u + (ty == 1 ? 512 : (ty == 2 ? 1024 : 0))) * 256 + (k - 1024);
                }
            }
            if (src) {
                breg[ks] = cvt8(src);
            } else {
                bf16x8 z;
                #pragma unroll
                for (int j = 0; j < 8; ++j) z[j] = (__bf16)0.0f;
                breg[ks] = z;
            }
        }
    }

    // ---------------------------- per-thread epilogue role + bias registers
    const int ebl = th & 31, ep = (th >> 5) & 3, elay = th >> 7;  // (lay,p,b)
    const int eu = cg_ * 4 + ep;
    const int eb = bloc + ebl;
    float ebs0, ebs1, ebs2, ebs3;
    {
        const float* bi  = elay ? bih0 : bih1;
        const float* bhp = elay ? bhh0 : bhh1;
        ebs0 = bi[eu]        + bhp[eu];
        ebs1 = bi[512 + eu]  + bhp[512 + eu];
        ebs2 = bi[1024 + eu];
        ebs3 = bhp[1024 + eu];
    }
    float hprev[2] = {0.0f, 0.0f};   // fp32 carried h-state (ping-pong parity)

    // ------------------------------------------------- FC role (64 WGs)
    const bool is_fc = (cg_ >= 96);
    const int fcid = bh * 32 + (cg_ - 96);         // [0,64)
    const int fmt = fcid & 3, fnt = fcid >> 2;     // m-tile [0,4), n-tile [0,16)
    bf16x8 fcB[4];
    float fbias = 0.0f;
    if (is_fc) {
        const int n = fnt * 16 + (ln & 15);
        const int kb = v * 128 + ((ln >> 4) << 3);
        #pragma unroll
        for (int ks = 0; ks < 4; ++ks)
            fcB[ks] = cvt8(Wfc + n * 512 + kb + ks * 32);
        fbias = bfc[fnt * 16 + (th & 15)];
    }

    grid.sync();   // phase-0 S buffers visible grid-wide

    // ------------------------------------------------------------- time loop
    // Stage t (t<1024): GEMM on Sc -> h1(t) [elay==0] and h0(t+1) [elay==1];
    // x(t+2) -> Sn; FC WGs also emit out rows for time t-1. One sync/step.
    for (int t = -1; t <= 1024; ++t) {
        const unsigned short* Sc = Sbuf[(t + 1) & 1];
        unsigned short* Sn       = Sbuf[t & 1];

        if (t < 1024) {
            // GEMM: wave v covers k in [v*320, v*320+320)
            f32x16 acc;
            #pragma unroll
            for (int i = 0; i < 16; ++i) acc[i] = 0.0f;
            {
                const int m = ln & 31;
                const unsigned short* arow = Sc + (bloc + m) * 1280 + ((ln >> 5) << 3) + v * 320;
                #pragma unroll
                for (int ks = 0; ks < 20; ++ks) {
                    bf16x8 af = *(const bf16x8*)(arow + ks * 16);
                    acc = __builtin_amdgcn_mfma_f32_32x32x16_bf16(af, breg[ks], acc, 0, 0, 0);
                }
            }
            {   // partials -> LDS  (C: col=lane&31, row=(r&3)+8*(r>>2)+4*(lane>>5))
                const int col = ln & 31, rbase = (ln >> 5) << 2;
                #pragma unroll
                for (int r = 0; r < 16; ++r) {
                    int row = (r & 3) + ((r >> 2) << 3) + rbase;
                    ldsC[(v * 32 + row) * 33 + col] = acc[r];
                }
            }
            __syncthreads();

            {   // fused gate epilogue (fp32)
                const int cb = elay * 16 + ep;
                float d0 = 0.f, d1 = 0.f, d2 = 0.f, d3 = 0.f;
                #pragma unroll
                for (int w = 0; w < 4; ++w) {
                    const float* Cw = ldsC + (w * 32 + ebl) * 33;
                    d0 += Cw[cb];       // r
                    d1 += Cw[cb + 4];   // z
                    d2 += Cw[cb + 8];   // n_x
                    d3 += Cw[cb + 12];  // n_h
                }
                float rg = fsig(d0 + ebs0);
                float zg = fsig(d1 + ebs1);
                float ng = ftanh((d2 + ebs2) + rg * (d3 + ebs3));
                float hold = hprev[(t + 1) & 1];
                float hnew = ng + zg * (hold - ng);
                if (elay == 1) {                       // layer 0 -> h0(t+1)
                    hprev[t & 1] = hnew;
                    Sn[eb * 1280 + eu] = f2b(hnew);
                } else if (t >= 0) {                   // layer 1 -> h1(t)
                    hprev[t & 1] = hnew;
                    Sn[eb * 1280 + 512 + eu] = f2b(hnew);
                }
            }
            // x(t+2) -> S_next x-region, fp32 -> bf16 (cg_==0 WGs, 1/batch-half)
            if (cg_ == 0 && (t + 2) < 1024) {
                int b = bloc + (th >> 3), ic = (th & 7) * 32;
                const float* src = xin + (b * 1024 + (t + 2)) * 256 + ic;
                unsigned short* dst = Sn + b * 1280 + 1024 + ic;
                #pragma unroll
                for (int q = 0; q < 4; ++q) {
                    union { u16x8 u; bf16x8 bv; } cv;
                    cv.bv = cvt8(src + q * 8);
                    *(u16x8*)(dst + q * 8) = cv.u;
                }
            }
        }

        // -------- fused FC for time t-1: out[(t-1)*64 + b][n] from Sc h1-region
        if (is_fc && t >= 1) {
            f32x4 fa;
            #pragma unroll
            for (int i = 0; i < 4; ++i) fa[i] = 0.0f;
            const unsigned short* Ar = Sc + (fmt * 16 + (ln & 15)) * 1280 + 512
                                       + v * 128 + ((ln >> 4) << 3);
            #pragma unroll
            for (int ks = 0; ks < 4; ++ks) {
                bf16x8 af = *(const bf16x8*)(Ar + ks * 32);
                fa = __builtin_amdgcn_mfma_f32_16x16x32_bf16(af, fcB[ks], fa, 0, 0, 0);
            }
            __syncthreads();                 // epilogue LDS reads done; reuse ldsC
            {   // C: col=lane&15, row=(lane>>4)*4+r   -> ldsC[v][16][17]
                const int col = ln & 15, rb = (ln >> 4) << 2;
                #pragma unroll
                for (int r = 0; r < 4; ++r)
                    ldsC[(v * 16 + rb + r) * 17 + col] = fa[r];
            }
            __syncthreads();
            {
                const int row = th >> 4, col = th & 15;
                float s = ldsC[row * 17 + col] + ldsC[(16 + row) * 17 + col]
                        + ldsC[(32 + row) * 17 + col] + ldsC[(48 + row) * 17 + col];
                out[((t - 1) * 64 + fmt * 16 + row) * 256 + fnt * 16 + col] = s + fbias;
            }
        }

        if (t < 1024) grid.sync();
    }
}

extern "C" void kernel_launch(void* const* d_in, const int* in_sizes, int n_in,
                              void* d_out, int out_size, void* d_ws, size_t ws_size,
                              hipStream_t stream) {
    (void)in_sizes; (void)n_in; (void)out_size; (void)d_ws; (void)ws_size;
    const float* xin  = (const float*)d_in[0];
    const float* Wih0 = (const float*)d_in[1];
    const float* bih0 = (const float*)d_in[2];
    const float* Whh0 = (const float*)d_in[3];
    const float* bhh0 = (const float*)d_in[4];
    const float* Wih1 = (const float*)d_in[5];
    const float* bih1 = (const float*)d_in[6];
    const float* Whh1 = (const float*)d_in[7];
    const float* bhh1 = (const float*)d_in[8];
    const float* Wfc  = (const float*)d_in[9];
    const float* bfc  = (const float*)d_in[10];
    float* outp = (float*)d_out;
    void* args[] = {&xin, &Wih0, &bih0, &Whh0, &bhh0, &Wih1, &bih1,
                    &Whh1, &bhh1, &Wfc, &bfc, &outp};
    hipLaunchCooperativeKernel((void*)gru_fused, dim3(256), dim3(256),
                               args, 0, stream);
}

// Round 5
// 21124.428 us; speedup vs baseline: 1.8181x; 1.8181x over previous
//
#include <hip/hip_runtime.h>

// ---------------------------------------------------------------------------
// GRU (2-layer, B=64, T=1024, I=256, H=512) + FC(512->256). FP32 I/O,
// bf16 MFMA internally (2%-relative threshold allows it; R4 passed 1.95e-3).
// Persistent cooperative kernel, 256 WGs x 256 thr. Per step one uniform MFMA
// GEMM C[64x4096] = A[64x1280] * Wp^T, A = [h0 | h1 | x(t+1)] staged bf16.
// R5 change vs R4: replace cg::grid.sync() (full L2 wbinv/step -> 1.7 MB/step
// HBM traffic, 37 us/step) with sc1-coherent data path (agent-scope relaxed
// atomics, write-through L3) + bare 2-level atomic tree barrier in d_ws.
// No cache-maintenance instructions in the loop at all.
// ---------------------------------------------------------------------------

typedef __bf16 bf16x8 __attribute__((ext_vector_type(8)));
typedef float f32x16 __attribute__((ext_vector_type(16)));
typedef float f32x4  __attribute__((ext_vector_type(4)));

// S ping-pong buffers: [2][64 b][1280 k] bf16 (fully rewritten every launch)
__device__ __align__(16) unsigned short g_S[2 * 64 * 1280];

__device__ __forceinline__ unsigned short f2b(float f) {
    unsigned u = __float_as_uint(f);
    u += 0x7fffu + ((u >> 16) & 1u);          // round to nearest even
    return (unsigned short)(u >> 16);
}
__device__ __forceinline__ unsigned int pack2(float a, float b) {
    return (unsigned)f2b(a) | ((unsigned)f2b(b) << 16);
}
// Agent-scope (cross-XCD coherent, L3) relaxed accessors
__device__ __forceinline__ void st32(void* p, unsigned int v) {
    __hip_atomic_store((unsigned int*)p, v, __ATOMIC_RELAXED, __HIP_MEMORY_SCOPE_AGENT);
}
__device__ __forceinline__ unsigned long long ld64(const void* p) {
    return __hip_atomic_load((const unsigned long long*)p, __ATOMIC_RELAXED,
                             __HIP_MEMORY_SCOPE_AGENT);
}
__device__ __forceinline__ bf16x8 ldfrag(const unsigned short* p) {   // 16B, L3-coherent
    union { unsigned long long q[2]; bf16x8 b; } cv;
    cv.q[0] = ld64(p);
    cv.q[1] = ld64(p + 4);
    return cv.b;
}
__device__ __forceinline__ float fsig(float x)  { return 1.0f / (1.0f + __expf(-x)); }
__device__ __forceinline__ float ftanh(float x) { return 1.0f - 2.0f / (__expf(2.0f * x) + 1.0f); }

__global__ __launch_bounds__(256, 1)
void gru_fused(const float* __restrict__ xin,   // [64][1024][256] fp32
               const float* __restrict__ Wih0, const float* __restrict__ bih0,
               const float* __restrict__ Whh0, const float* __restrict__ bhh0,
               const float* __restrict__ Wih1, const float* __restrict__ bih1,
               const float* __restrict__ Whh1, const float* __restrict__ bhh1,
               const float* __restrict__ Wfc,  const float* __restrict__ bfc,
               float* __restrict__ out, unsigned int* __restrict__ bar)
{
    __shared__ float ldsC[4224];          // [4 waves][32 rows][33] (pad: conflict-free)

    const int th = threadIdx.x;
    const int wg = blockIdx.x;            // 256 WGs (cooperative: co-resident)
    const int bh = wg >> 7;               // batch half
    const int cg_ = wg & 127;             // column group: units 4cg..4cg+3, both layers
    const int v  = th >> 6;               // wave = K-split (320 k each)
    const int ln = th & 63;
    const int tid = wg * 256 + th;
    const int bloc = bh * 32;

    unsigned short* Sbuf0 = g_S;                  // [64 b][1280 k] bf16
    unsigned short* Sbuf1 = g_S + 64 * 1280;
    unsigned short* Sbuf[2] = {Sbuf0, Sbuf1};

    unsigned int* grp    = bar;           // 8 counters, 128 B apart
    unsigned int* master = bar + 512;     // offset 2048 B

    unsigned int gen = 0;
    auto gridbar = [&]() {
        __syncthreads();                  // emits s_waitcnt vmcnt(0): sc1 stores at L3
        gen++;
        if (th == 0) {
            unsigned old = __hip_atomic_fetch_add(&grp[(wg & 7) * 32], 1u,
                              __ATOMIC_RELAXED, __HIP_MEMORY_SCOPE_AGENT);
            if ((old & 31u) == 31u)       // 32nd arrival of this group this gen
                __hip_atomic_fetch_add(master, 1u,
                              __ATOMIC_RELAXED, __HIP_MEMORY_SCOPE_AGENT);
            while (__hip_atomic_load(master, __ATOMIC_RELAXED,
                                     __HIP_MEMORY_SCOPE_AGENT) < gen * 8u)
                __builtin_amdgcn_s_sleep(1);
        }
        __syncthreads();
    };

    // ------------------------------------------------------------------ phase 0
    // zero h-regions (k<1024) of both S buffers (u32 sc1 stores)
    {   // 2 bufs x 64 b x 512 u32 = 65536 u32 = exactly one per thread
        int buf = tid >> 15, rem = tid & 32767, b = rem >> 9, kp = rem & 511;
        st32(Sbuf[buf] + b * 1280 + kp * 2, 0u);
    }
    // x(0) -> S0 x-region: 64 b x 128 u32 = 8192
    if (tid < 8192) {
        int b = tid >> 7, i = (tid & 127) * 2;
        const float* s = xin + (b * 1024 + 0) * 256 + i;
        st32(Sbuf0 + b * 1280 + 1024 + i, pack2(s[0], s[1]));
    }

    // ------------------------- preload B-fragments from GLOBAL (fp32 -> bf16)
    // column n = cg*32 + nl; nl = lay*16 + ty*4 + p (lay 0=layer1, 1=layer0;
    // ty 0=r,1=z,2=n_x,3=n_h); k = v*320 + ks*16 + (ln>>5)*8 + j.
    // k-regions: [0,512)=h0, [512,1024)=h1, [1024,1280)=x.
    bf16x8 breg[20];
    {
        const int nl = ln & 31, lay = nl >> 4, ty = (nl >> 2) & 3, p = nl & 3;
        const int u = cg_ * 4 + p;
        const int kh = (ln >> 5) << 3;
        #pragma unroll
        for (int ks = 0; ks < 20; ++ks) {
            const int k = v * 320 + ks * 16 + kh;
            const float* src = nullptr;
            if (lay == 0) {                    // layer 1: input = h0, hidden = h1
                if (k < 512) {
                    if (ty != 3) src = Wih1 + (u + (ty == 1 ? 512 : (ty == 2 ? 1024 : 0))) * 512 + k;
                } else if (k < 1024) {
                    if (ty != 2) src = Whh1 + (u + (ty == 1 ? 512 : (ty == 3 ? 1024 : 0))) * 512 + (k - 512);
                }
            } else {                           // layer 0: hidden = h0, input = x
                if (k < 512) {
                    if (ty != 2) src = Whh0 + (u + (ty == 1 ? 512 : (ty == 3 ? 1024 : 0))) * 512 + k;
                } else if (k >= 1024) {
                    if (ty != 3) src = Wih0 + (u + (ty == 1 ? 512 : (ty == 2 ? 1024 : 0))) * 256 + (k - 1024);
                }
            }
            bf16x8 z;
            #pragma unroll
            for (int j = 0; j < 8; ++j) z[j] = (__bf16)0.0f;
            if (src) {
                #pragma unroll
                for (int j = 0; j < 8; ++j) z[j] = (__bf16)src[j];
            }
            breg[ks] = z;
        }
    }

    // -------------------- epilogue roles: 128 threads x 2 adjacent units each
    const int ebl = th & 31;              // batch lane
    const int eq  = (th >> 5) & 1;        // unit-pair (p = 2q, 2q+1)
    const int elay = (th >> 6) & 1;       // 0 = layer1, 1 = layer0
    const int u0 = cg_ * 4 + 2 * eq;
    const int eb = bloc + ebl;
    float ebs[2][4];
    {
        const float* bi  = elay ? bih0 : bih1;
        const float* bhp = elay ? bhh0 : bhh1;
        #pragma unroll
        for (int s = 0; s < 2; ++s) {
            int u = u0 + s;
            ebs[s][0] = bi[u]        + bhp[u];
            ebs[s][1] = bi[512 + u]  + bhp[512 + u];
            ebs[s][2] = bi[1024 + u];
            ebs[s][3] = bhp[1024 + u];
        }
    }
    float hprev[2][2] = {{0.f, 0.f}, {0.f, 0.f}};   // [unit][parity] fp32 state

    // ------------------------------------------------- FC role (64 WGs)
    const bool is_fc = (cg_ >= 96);
    const int fcid = bh * 32 + (cg_ - 96);         // [0,64)
    const int fmt = fcid & 3, fnt = fcid >> 2;     // m-tile [0,4), n-tile [0,16)
    bf16x8 fcB[4];
    float fbias = 0.0f;
    if (is_fc) {
        const int n = fnt * 16 + (ln & 15);
        const int kb = v * 128 + ((ln >> 4) << 3);
        #pragma unroll
        for (int ks = 0; ks < 4; ++ks) {
            const float* src = Wfc + n * 512 + kb + ks * 32;
            bf16x8 z;
            #pragma unroll
            for (int j = 0; j < 8; ++j) z[j] = (__bf16)src[j];
            fcB[ks] = z;
        }
        fbias = bfc[fnt * 16 + (th & 15)];
    }

    gridbar();   // phase-0 S buffers visible grid-wide

    // ------------------------------------------------------------- time loop
    for (int t = -1; t <= 1024; ++t) {
        const unsigned short* Sc = Sbuf[(t + 1) & 1];
        unsigned short* Sn       = Sbuf[t & 1];

        if (t < 1024) {
            // GEMM: wave v covers k in [v*320, v*320+320)
            f32x16 acc;
            #pragma unroll
            for (int i = 0; i < 16; ++i) acc[i] = 0.0f;
            {
                const int m = ln & 31;
                const unsigned short* arow = Sc + (bloc + m) * 1280 + ((ln >> 5) << 3) + v * 320;
                #pragma unroll
                for (int ks = 0; ks < 20; ++ks) {
                    bf16x8 af = ldfrag(arow + ks * 16);
                    acc = __builtin_amdgcn_mfma_f32_32x32x16_bf16(af, breg[ks], acc, 0, 0, 0);
                }
            }
            {   // partials -> LDS  (C: col=lane&31, row=(r&3)+8*(r>>2)+4*(lane>>5))
                const int col = ln & 31, rbase = (ln >> 5) << 2;
                #pragma unroll
                for (int r = 0; r < 16; ++r) {
                    int row = (r & 3) + ((r >> 2) << 3) + rbase;
                    ldsC[(v * 32 + row) * 33 + col] = acc[r];
                }
            }
            __syncthreads();

            if (th < 128) {   // fused gate epilogue: 2 units per thread
                const int cb0 = elay * 16 + 2 * eq;
                float d[2][4];
                #pragma unroll
                for (int s = 0; s < 2; ++s)
                    #pragma unroll
                    for (int g = 0; g < 4; ++g) d[s][g] = 0.0f;
                #pragma unroll
                for (int w = 0; w < 4; ++w) {
                    const float* Cw = ldsC + (w * 32 + ebl) * 33;
                    #pragma unroll
                    for (int s = 0; s < 2; ++s)
                        #pragma unroll
                        for (int g = 0; g < 4; ++g)
                            d[s][g] += Cw[cb0 + s + g * 4];
                }
                float hn[2];
                #pragma unroll
                for (int s = 0; s < 2; ++s) {
                    float rg = fsig(d[s][0] + ebs[s][0]);
                    float zg = fsig(d[s][1] + ebs[s][1]);
                    float ng = ftanh((d[s][2] + ebs[s][2]) + rg * (d[s][3] + ebs[s][3]));
                    float hold = hprev[s][(t + 1) & 1];
                    hn[s] = ng + zg * (hold - ng);
                }
                if (elay == 1) {                       // layer 0 -> h0(t+1)
                    hprev[0][t & 1] = hn[0]; hprev[1][t & 1] = hn[1];
                    st32(Sn + eb * 1280 + u0, pack2(hn[0], hn[1]));
                } else if (t >= 0) {                   // layer 1 -> h1(t)
                    hprev[0][t & 1] = hn[0]; hprev[1][t & 1] = hn[1];
                    st32(Sn + eb * 1280 + 512 + u0, pack2(hn[0], hn[1]));
                }
            }
            // x(t+2) -> S_next x-region (cg_==0 WGs, one per batch half)
            if (cg_ == 0 && (t + 2) < 1024) {
                int b = bloc + (th >> 3), ic = (th & 7) * 32;
                const float* src = xin + (b * 1024 + (t + 2)) * 256 + ic;
                unsigned short* dst = Sn + b * 1280 + 1024 + ic;
                #pragma unroll
                for (int q = 0; q < 16; ++q)
                    st32(dst + q * 2, pack2(src[q * 2], src[q * 2 + 1]));
            }
        }

        // -------- fused FC for time t-1: out[(t-1)*64 + b][n] from Sc h1-region
        if (is_fc && t >= 1) {
            f32x4 fa;
            #pragma unroll
            for (int i = 0; i < 4; ++i) fa[i] = 0.0f;
            const unsigned short* Ar = Sc + (fmt * 16 + (ln & 15)) * 1280 + 512
                                       + v * 128 + ((ln >> 4) << 3);
            #pragma unroll
            for (int ks = 0; ks < 4; ++ks) {
                bf16x8 af = ldfrag(Ar + ks * 32);
                fa = __builtin_amdgcn_mfma_f32_16x16x32_bf16(af, fcB[ks], fa, 0, 0, 0);
            }
            __syncthreads();                 // epilogue LDS reads done; reuse ldsC
            {   // C: col=lane&15, row=(lane>>4)*4+r   -> ldsC[v][16][17]
                const int col = ln & 15, rb = (ln >> 4) << 2;
                #pragma unroll
                for (int r = 0; r < 4; ++r)
                    ldsC[(v * 16 + rb + r) * 17 + col] = fa[r];
            }
            __syncthreads();
            {
                const int row = th >> 4, col = th & 15;
                float s = ldsC[row * 17 + col] + ldsC[(16 + row) * 17 + col]
                        + ldsC[(32 + row) * 17 + col] + ldsC[(48 + row) * 17 + col];
                out[((t - 1) * 64 + fmt * 16 + row) * 256 + fnt * 16 + col] = s + fbias;
            }
        }

        if (t < 1024) gridbar();
    }
}

extern "C" void kernel_launch(void* const* d_in, const int* in_sizes, int n_in,
                              void* d_out, int out_size, void* d_ws, size_t ws_size,
                              hipStream_t stream) {
    (void)in_sizes; (void)n_in; (void)out_size; (void)ws_size;
    hipMemsetAsync(d_ws, 0, 4096, stream);   // barrier counters (monotonic per launch)
    const float* xin  = (const float*)d_in[0];
    const float* Wih0 = (const float*)d_in[1];
    const float* bih0 = (const float*)d_in[2];
    const float* Whh0 = (const float*)d_in[3];
    const float* bhh0 = (const float*)d_in[4];
    const float* Wih1 = (const float*)d_in[5];
    const float* bih1 = (const float*)d_in[6];
    const float* Whh1 = (const float*)d_in[7];
    const float* bhh1 = (const float*)d_in[8];
    const float* Wfc  = (const float*)d_in[9];
    const float* bfc  = (const float*)d_in[10];
    float* outp = (float*)d_out;
    unsigned int* barp = (unsigned int*)d_ws;
    void* args[] = {&xin, &Wih0, &bih0, &Whh0, &bhh0, &Wih1, &bih1,
                    &Whh1, &bhh1, &Wfc, &bfc, &outp, &barp};
    hipLaunchCooperativeKernel((void*)gru_fused, dim3(256), dim3(256),
                               args, 0, stream);
}